// Round 4
// baseline (25.914 us; speedup 1.0000x reference)
//
#include <hip/hip_runtime.h>

#define BAGS       16384
#define KIN        13
// 32 lanes per bag, 8 bags per 256-thread block -> 2048 EB blocks
#define EB_BLOCKS  (BAGS / 8)
#define MLP_BLOCKS (BAGS / 256)

// 16-byte vector load legal at 4-byte alignment (multi-dword global loads
// need only dword alignment on gfx9+). w component is discarded.
struct __attribute__((packed, aligned(4))) F4 { float x, y, z, w; };

__global__ __launch_bounds__(256) void fused_kernel(
    const int* __restrict__ idxs, const int* __restrict__ offs,
    const float* __restrict__ W, const float* __restrict__ x,
    const float* __restrict__ w0, const float* __restrict__ b0,
    const float* __restrict__ w1, const float* __restrict__ b1,
    const float* __restrict__ w2, const float* __restrict__ b2,
    float* __restrict__ out, int n_total, int V)
{
    if (blockIdx.x < EB_BLOCKS) {
        // ---- EmbeddingBag mean: 32 lanes per bag ----
        int bag = (int)(blockIdx.x * 8 + (threadIdx.x >> 5));
        int sl  = (int)(threadIdx.x & 31);

        int start = offs[bag];
        int end   = (bag + 1 < BAGS) ? offs[bag + 1] : n_total;
        int cnt   = end - start;
        int Vm1   = V - 1;

        float s0 = 0.f, s1 = 0.f, s2 = 0.f;

        if (cnt == 50) {
            // lanes 0..31 handle slot sl; lanes 0..17 also handle slot sl+32
            int i0 = start + sl;
            int ia = __builtin_nontemporal_load(&idxs[i0]);
            bool two = (sl < 18);
            int ib = two ? __builtin_nontemporal_load(&idxs[i0 + 32]) : 0;

            if (ia < Vm1) {
                F4 ra = *(const F4*)(W + (size_t)ia * 3);
                s0 = ra.x; s1 = ra.y; s2 = ra.z;
            } else {
                const float* r = W + (size_t)ia * 3;
                s0 = r[0]; s1 = r[1]; s2 = r[2];
            }
            if (two) {
                if (ib < Vm1) {
                    F4 rb = *(const F4*)(W + (size_t)ib * 3);
                    s0 += rb.x; s1 += rb.y; s2 += rb.z;
                } else {
                    const float* r = W + (size_t)ib * 3;
                    s0 += r[0]; s1 += r[1]; s2 += r[2];
                }
            }
        } else {
            for (int i = start + sl; i < end; i += 32) {
                int idx = idxs[i];
                if (idx < Vm1) {
                    F4 r = *(const F4*)(W + (size_t)idx * 3);
                    s0 += r.x; s1 += r.y; s2 += r.z;
                } else {
                    const float* r = W + (size_t)idx * 3;
                    s0 += r[0]; s1 += r[1]; s2 += r[2];
                }
            }
        }

        // butterfly reduce within each 32-lane group
        #pragma unroll
        for (int m = 16; m >= 1; m >>= 1) {
            s0 += __shfl_xor(s0, m, 32);
            s1 += __shfl_xor(s1, m, 32);
            s2 += __shfl_xor(s2, m, 32);
        }

        if (sl < 9) {
            float inv = 1.0f / (float)cnt;
            int c = sl % 3;  // out columns 0..8 are (e0,e1,e2) x3
            float e = (c == 0 ? s0 : (c == 1 ? s1 : s2)) * inv;
            out[(size_t)bag * 12 + sl] = e;
        }
    } else {
        // ---- MLP: one thread per bag, 13 -> 12 -> 6 -> 3 affine ----
        int b = (int)((blockIdx.x - EB_BLOCKS) * 256 + threadIdx.x);
        if (b >= BAGS) return;

        float xi[KIN];
        #pragma unroll
        for (int k = 0; k < KIN; ++k) xi[k] = x[(size_t)b * KIN + k];

        float h0[12];
        #pragma unroll
        for (int j = 0; j < 12; ++j) {
            float acc = b0[j];
            #pragma unroll
            for (int k = 0; k < KIN; ++k) acc += w0[j * KIN + k] * xi[k];
            h0[j] = acc;
        }

        float h1[6];
        #pragma unroll
        for (int j = 0; j < 6; ++j) {
            float acc = b1[j];
            #pragma unroll
            for (int k = 0; k < 12; ++k) acc += w1[j * 12 + k] * h0[k];
            h1[j] = acc;
        }

        float* o = out + (size_t)b * 12 + 9;
        #pragma unroll
        for (int j = 0; j < 3; ++j) {
            float acc = b2[j];
            #pragma unroll
            for (int k = 0; k < 6; ++k) acc += w2[j * 6 + k] * h1[k];
            o[j] = acc;
        }
    }
}

extern "C" void kernel_launch(void* const* d_in, const int* in_sizes, int n_in,
                              void* d_out, int out_size, void* d_ws, size_t ws_size,
                              hipStream_t stream) {
    const int*   eb_input   = (const int*)  d_in[0];   // [N]
    const int*   eb_offset  = (const int*)  d_in[1];   // [B]
    const float* mlp_input  = (const float*)d_in[2];   // [B,13]
    const float* emb_weight = (const float*)d_in[3];   // [V,3]
    const float* w0 = (const float*)d_in[4];
    const float* b0 = (const float*)d_in[5];
    const float* w1 = (const float*)d_in[6];
    const float* b1 = (const float*)d_in[7];
    const float* w2 = (const float*)d_in[8];
    const float* b2 = (const float*)d_in[9];
    float* out = (float*)d_out;

    int n_total = in_sizes[0];
    int V = in_sizes[3] / 3;

    fused_kernel<<<EB_BLOCKS + MLP_BLOCKS, 256, 0, stream>>>(
        eb_input, eb_offset, emb_weight, mlp_input,
        w0, b0, w1, b1, w2, b2, out, n_total, V);
}